// Round 1
// baseline (434.530 us; speedup 1.0000x reference)
//
#include <hip/hip_runtime.h>
#include <math.h>

#define B_ 4
#define T_ 2048
#define C_ 1024
#define H_ 128
#define SCALE 0.088388347648318447f   // 1/sqrt(128)

// ---------------------------------------------------------------------------
// QKV projection: out = x @ W for W in {Wq, Wk, Wv} (selected by blockIdx.y).
// x: [8192, 1024], W: [1024, 128], out: [8192, 128]
// grid (128, 3), block 256. Tile: 64 rows x 128 cols, K-step 32.
// ---------------------------------------------------------------------------
__global__ __launch_bounds__(256) void qkv_gemm_kernel(
    const float* __restrict__ x,
    const float* __restrict__ Wq, const float* __restrict__ Wk, const float* __restrict__ Wv,
    float* __restrict__ qo, float* __restrict__ ko, float* __restrict__ vo)
{
    __shared__ float xs[64][33];     // +1 pad: column reads conflict-free
    __shared__ float ws[32][128];

    const int tid = threadIdx.x;
    const int m0  = blockIdx.x * 64;
    const float* W   = (blockIdx.y == 0) ? Wq : (blockIdx.y == 1) ? Wk : Wv;
    float*       out = (blockIdx.y == 0) ? qo : (blockIdx.y == 1) ? ko : vo;

    const int r0 = (tid >> 4) * 4;   // 4 rows per thread
    const int c0 = (tid & 15) * 8;   // 8 cols per thread

    float acc[4][8];
#pragma unroll
    for (int i = 0; i < 4; ++i)
#pragma unroll
        for (int j = 0; j < 8; ++j) acc[i][j] = 0.f;

    for (int k0 = 0; k0 < C_; k0 += 32) {
        // stage x tile 64x32 (512 float4)
        for (int it = tid; it < 512; it += 256) {
            const int row = it >> 3, c4 = (it & 7) * 4;
            float4 t = *(const float4*)&x[(size_t)(m0 + row) * C_ + k0 + c4];
            xs[row][c4 + 0] = t.x; xs[row][c4 + 1] = t.y;
            xs[row][c4 + 2] = t.z; xs[row][c4 + 3] = t.w;
        }
        // stage W tile 32x128 (1024 float4)
        for (int it = tid; it < 1024; it += 256) {
            const int row = it >> 5, c4 = (it & 31) * 4;
            *(float4*)&ws[row][c4] = *(const float4*)&W[(size_t)(k0 + row) * H_ + c4];
        }
        __syncthreads();

#pragma unroll 8
        for (int kk = 0; kk < 32; ++kk) {
            float a[4];
#pragma unroll
            for (int i = 0; i < 4; ++i) a[i] = xs[r0 + i][kk];
            const float4 b0 = *(const float4*)&ws[kk][c0];
            const float4 b1 = *(const float4*)&ws[kk][c0 + 4];
            float bb[8] = {b0.x, b0.y, b0.z, b0.w, b1.x, b1.y, b1.z, b1.w};
#pragma unroll
            for (int i = 0; i < 4; ++i)
#pragma unroll
                for (int j = 0; j < 8; ++j)
                    acc[i][j] = fmaf(a[i], bb[j], acc[i][j]);
        }
        __syncthreads();
    }

    float* ob = out + (size_t)m0 * H_;
#pragma unroll
    for (int i = 0; i < 4; ++i) {
        *(float4*)&ob[(r0 + i) * H_ + c0]     = make_float4(acc[i][0], acc[i][1], acc[i][2], acc[i][3]);
        *(float4*)&ob[(r0 + i) * H_ + c0 + 4] = make_float4(acc[i][4], acc[i][5], acc[i][6], acc[i][7]);
    }
}

// ---------------------------------------------------------------------------
// Flash attention (causal), fp32. grid (T_/32, B_), block 256.
// Each block: 32 query rows; iterates k/v tiles of 32 rows up to the diagonal.
// ---------------------------------------------------------------------------
__global__ __launch_bounds__(256) void attn_kernel(
    const float* __restrict__ q, const float* __restrict__ k, const float* __restrict__ v,
    float* __restrict__ out)
{
    __shared__ float qs[32][132];   // 132 = 128+4: keeps float4 alignment, breaks bank stride
    __shared__ float ks[32][132];
    __shared__ float vs[32][132];
    __shared__ float ps[32][36];
    __shared__ float mrow[32], lrow[32], frow[32];

    const int tid = threadIdx.x;
    const int jt  = blockIdx.x;   // q tile index
    const int b   = blockIdx.y;

    const float* qb = q + ((size_t)b * T_ + (size_t)jt * 32) * H_;
    const float* kb = k + (size_t)b * T_ * H_;
    const float* vb = v + (size_t)b * T_ * H_;

    // stage q tile (32 x 128)
    for (int it = tid; it < 1024; it += 256) {
        const int row = it >> 5, c4 = (it & 31) * 4;
        *(float4*)&qs[row][c4] = *(const float4*)&qb[row * H_ + c4];
    }
    if (tid < 32) { mrow[tid] = -INFINITY; lrow[tid] = 0.f; frow[tid] = 0.f; }

    const int sr = (tid >> 4) * 2;  // 2 rows per thread (S rows == O rows)
    const int tc = tid & 15;

    float o[2][8];
#pragma unroll
    for (int i = 0; i < 2; ++i)
#pragma unroll
        for (int j = 0; j < 8; ++j) o[i][j] = 0.f;

    const int ntiles = jt + 1;
    for (int kt = 0; kt < ntiles; ++kt) {
        __syncthreads();   // protect ks/vs/ps (and q staging on iter 0)

        const float* kbt = kb + (size_t)kt * 32 * H_;
        const float* vbt = vb + (size_t)kt * 32 * H_;
        for (int it = tid; it < 1024; it += 256) {
            const int row = it >> 5, c4 = (it & 31) * 4;
            *(float4*)&ks[row][c4] = *(const float4*)&kbt[row * H_ + c4];
            *(float4*)&vs[row][c4] = *(const float4*)&vbt[row * H_ + c4];
        }
        __syncthreads();

        // S micro-tile: rows {sr, sr+1} x cols {tc, tc+16}
        float s00 = 0.f, s01 = 0.f, s10 = 0.f, s11 = 0.f;
#pragma unroll 4
        for (int d = 0; d < H_; d += 4) {
            const float4 q0 = *(const float4*)&qs[sr][d];
            const float4 q1 = *(const float4*)&qs[sr + 1][d];
            const float4 k0 = *(const float4*)&ks[tc][d];
            const float4 k1 = *(const float4*)&ks[tc + 16][d];
            s00 = fmaf(q0.x, k0.x, s00); s00 = fmaf(q0.y, k0.y, s00);
            s00 = fmaf(q0.z, k0.z, s00); s00 = fmaf(q0.w, k0.w, s00);
            s01 = fmaf(q0.x, k1.x, s01); s01 = fmaf(q0.y, k1.y, s01);
            s01 = fmaf(q0.z, k1.z, s01); s01 = fmaf(q0.w, k1.w, s01);
            s10 = fmaf(q1.x, k0.x, s10); s10 = fmaf(q1.y, k0.y, s10);
            s10 = fmaf(q1.z, k0.z, s10); s10 = fmaf(q1.w, k0.w, s10);
            s11 = fmaf(q1.x, k1.x, s11); s11 = fmaf(q1.y, k1.y, s11);
            s11 = fmaf(q1.z, k1.z, s11); s11 = fmaf(q1.w, k1.w, s11);
        }
        {
            const int qg0 = jt * 32 + sr, qg1 = qg0 + 1;
            const int kg0 = kt * 32 + tc, kg1 = kg0 + 16;
            ps[sr][tc]          = (kg0 <= qg0) ? s00 * SCALE : -INFINITY;
            ps[sr][tc + 16]     = (kg1 <= qg0) ? s01 * SCALE : -INFINITY;
            ps[sr + 1][tc]      = (kg0 <= qg1) ? s10 * SCALE : -INFINITY;
            ps[sr + 1][tc + 16] = (kg1 <= qg1) ? s11 * SCALE : -INFINITY;
        }
        __syncthreads();

        // online softmax: 8 lanes per row
        {
            const int row = tid >> 3, l = tid & 7;
            float e0 = ps[row][l],      e1 = ps[row][l + 8];
            float e2 = ps[row][l + 16], e3 = ps[row][l + 24];
            float mx = fmaxf(fmaxf(e0, e1), fmaxf(e2, e3));
            mx = fmaxf(mx, __shfl_xor(mx, 1));
            mx = fmaxf(mx, __shfl_xor(mx, 2));
            mx = fmaxf(mx, __shfl_xor(mx, 4));
            const float m_old = mrow[row];
            const float m_new = fmaxf(m_old, mx);
            const float p0 = __expf(e0 - m_new), p1 = __expf(e1 - m_new);
            const float p2 = __expf(e2 - m_new), p3 = __expf(e3 - m_new);
            ps[row][l]      = p0; ps[row][l + 8]  = p1;
            ps[row][l + 16] = p2; ps[row][l + 24] = p3;
            float sum = p0 + p1 + p2 + p3;
            sum += __shfl_xor(sum, 1);
            sum += __shfl_xor(sum, 2);
            sum += __shfl_xor(sum, 4);
            if (l == 0) {
                const float f = __expf(m_old - m_new);
                frow[row] = f;
                lrow[row] = lrow[row] * f + sum;
                mrow[row] = m_new;
            }
        }
        __syncthreads();

        // O update: O = O*f + P @ V  (cols tc*4..+3 and tc*4+64..+67)
        {
            const float f0 = frow[sr], f1 = frow[sr + 1];
#pragma unroll
            for (int j = 0; j < 8; ++j) { o[0][j] *= f0; o[1][j] *= f1; }
#pragma unroll 4
            for (int cp = 0; cp < 32; ++cp) {
                const float p0 = ps[sr][cp], p1 = ps[sr + 1][cp];
                const float4 v0 = *(const float4*)&vs[cp][tc * 4];
                const float4 v1 = *(const float4*)&vs[cp][tc * 4 + 64];
                o[0][0] = fmaf(p0, v0.x, o[0][0]); o[0][1] = fmaf(p0, v0.y, o[0][1]);
                o[0][2] = fmaf(p0, v0.z, o[0][2]); o[0][3] = fmaf(p0, v0.w, o[0][3]);
                o[0][4] = fmaf(p0, v1.x, o[0][4]); o[0][5] = fmaf(p0, v1.y, o[0][5]);
                o[0][6] = fmaf(p0, v1.z, o[0][6]); o[0][7] = fmaf(p0, v1.w, o[0][7]);
                o[1][0] = fmaf(p1, v0.x, o[1][0]); o[1][1] = fmaf(p1, v0.y, o[1][1]);
                o[1][2] = fmaf(p1, v0.z, o[1][2]); o[1][3] = fmaf(p1, v0.w, o[1][3]);
                o[1][4] = fmaf(p1, v1.x, o[1][4]); o[1][5] = fmaf(p1, v1.y, o[1][5]);
                o[1][6] = fmaf(p1, v1.z, o[1][6]); o[1][7] = fmaf(p1, v1.w, o[1][7]);
            }
        }
    }

    // epilogue: divide by l and store
    const float inv0 = 1.f / lrow[sr];
    const float inv1 = 1.f / lrow[sr + 1];
    float* ob = out + ((size_t)b * T_ + (size_t)jt * 32) * H_;
    *(float4*)&ob[sr * H_ + tc * 4]            = make_float4(o[0][0] * inv0, o[0][1] * inv0, o[0][2] * inv0, o[0][3] * inv0);
    *(float4*)&ob[sr * H_ + tc * 4 + 64]       = make_float4(o[0][4] * inv0, o[0][5] * inv0, o[0][6] * inv0, o[0][7] * inv0);
    *(float4*)&ob[(sr + 1) * H_ + tc * 4]      = make_float4(o[1][0] * inv1, o[1][1] * inv1, o[1][2] * inv1, o[1][3] * inv1);
    *(float4*)&ob[(sr + 1) * H_ + tc * 4 + 64] = make_float4(o[1][4] * inv1, o[1][5] * inv1, o[1][6] * inv1, o[1][7] * inv1);
}

extern "C" void kernel_launch(void* const* d_in, const int* in_sizes, int n_in,
                              void* d_out, int out_size, void* d_ws, size_t ws_size,
                              hipStream_t stream) {
    const float* x  = (const float*)d_in[0];
    const float* Wk = (const float*)d_in[1];
    const float* Wq = (const float*)d_in[2];
    const float* Wv = (const float*)d_in[3];
    float* out = (float*)d_out;

    const size_t n = (size_t)B_ * T_ * H_;   // 1,048,576 elements each
    float* qbuf = (float*)d_ws;
    float* kbuf = qbuf + n;
    float* vbuf = kbuf + n;

    qkv_gemm_kernel<<<dim3((B_ * T_) / 64, 3), 256, 0, stream>>>(
        x, Wq, Wk, Wv, qbuf, kbuf, vbuf);
    attn_kernel<<<dim3(T_ / 32, B_), 256, 0, stream>>>(qbuf, kbuf, vbuf, out);
}

// Round 2
// 98.436 us; speedup vs baseline: 4.4144x; 4.4144x over previous
//
#include <hip/hip_runtime.h>
#include <hip/hip_bf16.h>
#include <math.h>

#define B_ 4
#define T_ 2048
#define C_ 1024
#define H_ 128
#define SCALE 0.088388347648318447f   // 1/sqrt(128)

typedef unsigned short u16;
typedef __bf16 bf16x8 __attribute__((ext_vector_type(8)));
typedef __bf16 bf16x4 __attribute__((ext_vector_type(4)));
typedef float  f32x4  __attribute__((ext_vector_type(4)));
typedef u16    u16x8  __attribute__((ext_vector_type(8)));
typedef u16    u16x4  __attribute__((ext_vector_type(4)));

__device__ __forceinline__ u16 f2bf(float f) {
    __hip_bfloat16 h = __float2bfloat16(f);
    return __builtin_bit_cast(u16, h);
}

// async global->LDS, 16B per lane. lds dst must be wave-uniform base (HW adds lane*16).
__device__ __forceinline__ void load_lds16(const void* g, void* l) {
    __builtin_amdgcn_global_load_lds(
        (const __attribute__((address_space(1))) unsigned int*)g,
        (__attribute__((address_space(3))) unsigned int*)l, 16, 0, 0);
}

// ---------------------------------------------------------------------------
// convert x (fp32) -> xb (bf16), 8 elems/thread
// ---------------------------------------------------------------------------
__global__ __launch_bounds__(256) void convert_x(const float* __restrict__ x,
                                                 u16* __restrict__ xb) {
    const size_t i = ((size_t)blockIdx.x * 256 + threadIdx.x) * 8;
    const float4 a = *(const float4*)&x[i];
    const float4 b = *(const float4*)&x[i + 4];
    u16x8 r;
    r[0] = f2bf(a.x); r[1] = f2bf(a.y); r[2] = f2bf(a.z); r[3] = f2bf(a.w);
    r[4] = f2bf(b.x); r[5] = f2bf(b.y); r[6] = f2bf(b.z); r[7] = f2bf(b.w);
    *(u16x8*)&xb[i] = r;
}

// ---------------------------------------------------------------------------
// convert + transpose W: wbT[s][n][k] = W_s[k][n] (bf16), SCALE folded into Wq
// ---------------------------------------------------------------------------
__global__ __launch_bounds__(256) void convert_w(const float* __restrict__ Wq,
                                                 const float* __restrict__ Wk,
                                                 const float* __restrict__ Wv,
                                                 u16* __restrict__ wbT) {
    const int id = blockIdx.x * 256 + threadIdx.x;      // < 3*131072
    const int s = id >> 17;
    const int r = id & 131071;
    const int k = r >> 7, n = r & 127;
    const float* W = (s == 0) ? Wq : (s == 1) ? Wk : Wv;
    float v = W[k * 128 + n];
    if (s == 0) v *= SCALE;
    wbT[(s << 17) + (n << 10) + k] = f2bf(v);
}

// ---------------------------------------------------------------------------
// QKV GEMM, bf16 MFMA. grid (128, 3), block 256 (4 waves, 2x2).
// Tile 64(M) x 128(N), BK=64. q,k stored row-major bf16; v stored transposed.
// ---------------------------------------------------------------------------
__global__ __launch_bounds__(256) void gemm_qkv(
    const u16* __restrict__ xb, const u16* __restrict__ wbT,
    u16* __restrict__ qb, u16* __restrict__ kb, u16* __restrict__ vT)
{
    __shared__ u16 xs[4096];   // [64][64] bf16, 128B rows, swizzle ^((row&7)<<4)
    __shared__ u16 ws[8192];   // [128 n][64 k] bf16, 128B rows, same swizzle

    const int tid = threadIdx.x;
    const int w = tid >> 6, lane = tid & 63, lg = lane >> 4, lr = lane & 15;
    const int wm = w >> 1, wn = w & 1;
    const int s = blockIdx.y;
    const int m0 = blockIdx.x * 64;
    const u16* wsrc = wbT + (s << 17);

    f32x4 acc[2][4] = {};

    for (int k0 = 0; k0 < C_; k0 += 64) {
        __syncthreads();
        // stage x tile (8KB): 2 x 1KB chunks per wave, pre-swizzled source
#pragma unroll
        for (int i = 0; i < 2; ++i) {
            const unsigned o = (unsigned)(w * 2 + i) * 1024u + (unsigned)lane * 16u;
            const unsigned o2 = o ^ (((o >> 7) & 7u) << 4);
            const unsigned row = o2 >> 7, col = (o2 & 127u) >> 1;
            load_lds16(xb + (size_t)(m0 + row) * C_ + k0 + col, &xs[(w * 2 + i) * 512]);
        }
        // stage W^T tile (16KB): 4 chunks per wave
#pragma unroll
        for (int i = 0; i < 4; ++i) {
            const unsigned o = (unsigned)(w * 4 + i) * 1024u + (unsigned)lane * 16u;
            const unsigned o2 = o ^ (((o >> 7) & 7u) << 4);
            const unsigned row = o2 >> 7, col = (o2 & 127u) >> 1;
            load_lds16(wsrc + (size_t)row * C_ + k0 + col, &ws[(w * 4 + i) * 512]);
        }
        __syncthreads();

#pragma unroll
        for (int kc = 0; kc < 2; ++kc) {
            bf16x8 af[2], bfr[4];
#pragma unroll
            for (int mi = 0; mi < 2; ++mi) {
                const int row = wm * 32 + mi * 16 + lr;
                const unsigned byte = (unsigned)(kc * 64 + lg * 16) ^ (((unsigned)row & 7u) << 4);
                af[mi] = *(const bf16x8*)((const char*)xs + row * 128 + byte);
            }
#pragma unroll
            for (int ni = 0; ni < 4; ++ni) {
                const int n = wn * 64 + ni * 16 + lr;
                const unsigned byte = (unsigned)(kc * 64 + lg * 16) ^ (((unsigned)n & 7u) << 4);
                bfr[ni] = *(const bf16x8*)((const char*)ws + n * 128 + byte);
            }
#pragma unroll
            for (int mi = 0; mi < 2; ++mi)
#pragma unroll
                for (int ni = 0; ni < 4; ++ni)
                    acc[mi][ni] = __builtin_amdgcn_mfma_f32_16x16x32_bf16(
                        af[mi], bfr[ni], acc[mi][ni], 0, 0, 0);
        }
    }

    if (s < 2) {
        u16* dst = (s == 0) ? qb : kb;
#pragma unroll
        for (int mi = 0; mi < 2; ++mi)
#pragma unroll
            for (int ni = 0; ni < 4; ++ni) {
                const int trow = m0 + wm * 32 + mi * 16 + lg * 4;
                const int col = wn * 64 + ni * 16 + lr;
#pragma unroll
                for (int r = 0; r < 4; ++r)
                    dst[(size_t)(trow + r) * H_ + col] = f2bf(acc[mi][ni][r]);
            }
    } else {
        // v stored transposed: vT[b][d][t]
#pragma unroll
        for (int mi = 0; mi < 2; ++mi)
#pragma unroll
            for (int ni = 0; ni < 4; ++ni) {
                const int trow = m0 + wm * 32 + mi * 16 + lg * 4;
                const int bb = trow >> 11, t = trow & 2047;
                const int d = wn * 64 + ni * 16 + lr;
                u16x4 pk;
                pk[0] = f2bf(acc[mi][ni][0]); pk[1] = f2bf(acc[mi][ni][1]);
                pk[2] = f2bf(acc[mi][ni][2]); pk[3] = f2bf(acc[mi][ni][3]);
                *(u16x4*)&vT[((size_t)bb * 128 + d) * 2048 + t] = pk;
            }
    }
}

// ---------------------------------------------------------------------------
// Flash attention, bf16 MFMA, swapped QK^T. grid (64, 4), block 128 (2 waves).
// Wave w owns 16 q-rows (jt*32 + w*16 ..). KV tiles of 32.
// ---------------------------------------------------------------------------
__global__ __launch_bounds__(128) void attn_mfma(
    const u16* __restrict__ qb, const u16* __restrict__ kb,
    const u16* __restrict__ vT, float* __restrict__ out)
{
    __shared__ u16 ks[4096];        // [32][128] bf16, 256B rows, swizzle ^((row&7)<<4)
    __shared__ u16 vs[128 * 36];    // [128 d][32 kv] bf16, padded rows 72B (no XOR)

    const int tid = threadIdx.x;
    const int w = tid >> 6, lane = tid & 63, lg = lane >> 4, lr = lane & 15;
    const int jt = blockIdx.x, b = blockIdx.y;
    const int qrow_base = jt * 32 + w * 16;

    // Q fragments: d-slot map = kc*32 + lg*8 + j  (matches K-frag map)
    const u16* qp = qb + ((size_t)(b << 11) + qrow_base + lr) * H_;
    bf16x8 qf[4];
#pragma unroll
    for (int kc = 0; kc < 4; ++kc)
        qf[kc] = *(const bf16x8*)&qp[kc * 32 + lg * 8];

    f32x4 o[8] = {};
    float m_run = -INFINITY, l_run = 0.f;

    for (int kt = 0; kt <= jt; ++kt) {
        __syncthreads();   // protect prev tile's reads
        // stage K tile (8KB) via global_load_lds, pre-swizzled source
        const u16* kbase = kb + ((size_t)(b << 11) + kt * 32) * H_;
#pragma unroll
        for (int i = 0; i < 4; ++i) {
            const unsigned o_ = (unsigned)(w * 4 + i) * 1024u + (unsigned)lane * 16u;
            const unsigned o2 = o_ ^ (((o_ >> 8) & 7u) << 4);
            const unsigned row = o2 >> 8, colb = o2 & 255u;
            load_lds16((const char*)kbase + row * 256 + colb, &ks[(w * 4 + i) * 512]);
        }
        // stage V^T tile (reg-staged, padded rows)
        const u16* vbase = vT + (size_t)b * 128 * 2048 + (size_t)kt * 32;
#pragma unroll
        for (int i = 0; i < 4; ++i) {
            const int idx = i * 128 + tid;         // 0..511
            const int d = idx >> 2, c = idx & 3;
            const u16x8 tmp = *(const u16x8*)&vbase[(size_t)d * 2048 + c * 8];
            *(u16x8*)((char*)vs + d * 72 + c * 16) = tmp;
        }
        __syncthreads();

        // S^T = K @ Q^T : two 16-kv subtiles, accumulate over d (4 chunks of 32)
        f32x4 s0 = {0.f, 0.f, 0.f, 0.f}, s1 = {0.f, 0.f, 0.f, 0.f};
        const unsigned swz = ((unsigned)lr & 7u) << 4;
#pragma unroll
        for (int kc = 0; kc < 4; ++kc) {
            const unsigned byte = ((unsigned)(kc * 64 + lg * 16)) ^ swz;
            const bf16x8 kf0 = *(const bf16x8*)((const char*)ks + lr * 256 + byte);
            const bf16x8 kf1 = *(const bf16x8*)((const char*)ks + lr * 256 + 4096 + byte);
            s0 = __builtin_amdgcn_mfma_f32_16x16x32_bf16(kf0, qf[kc], s0, 0, 0, 0);
            s1 = __builtin_amdgcn_mfma_f32_16x16x32_bf16(kf1, qf[kc], s1, 0, 0, 0);
        }

        // causal mask (diagonal tile only). kv-offset = sub*16 + lg*4 + r, q-offset = w*16 + lr
        if (kt == jt) {
            const int qq = w * 16 + lr;
#pragma unroll
            for (int r = 0; r < 4; ++r) {
                if (lg * 4 + r > qq)      s0[r] = -INFINITY;
                if (16 + lg * 4 + r > qq) s1[r] = -INFINITY;
            }
        }

        // online softmax (q-row = lr, replicated across 4 lane-groups)
        float mt = fmaxf(fmaxf(fmaxf(s0[0], s0[1]), fmaxf(s0[2], s0[3])),
                         fmaxf(fmaxf(s1[0], s1[1]), fmaxf(s1[2], s1[3])));
        mt = fmaxf(mt, __shfl_xor(mt, 16));
        mt = fmaxf(mt, __shfl_xor(mt, 32));
        const float mn = fmaxf(m_run, mt);
        const float p0 = __expf(s0[0] - mn), p1 = __expf(s0[1] - mn);
        const float p2 = __expf(s0[2] - mn), p3 = __expf(s0[3] - mn);
        const float p4 = __expf(s1[0] - mn), p5 = __expf(s1[1] - mn);
        const float p6 = __expf(s1[2] - mn), p7 = __expf(s1[3] - mn);
        float sum = ((p0 + p1) + (p2 + p3)) + ((p4 + p5) + (p6 + p7));
        sum += __shfl_xor(sum, 16);
        sum += __shfl_xor(sum, 32);
        const float f = __expf(m_run - mn);   // first tile: exp(-inf)=0
        l_run = l_run * f + sum;
        m_run = mn;

        // rescale O: broadcast f per O-row ((lg*4+r) is the q-offset of acc reg r)
        const float fb0 = __shfl(f, lg * 4 + 0);
        const float fb1 = __shfl(f, lg * 4 + 1);
        const float fb2 = __shfl(f, lg * 4 + 2);
        const float fb3 = __shfl(f, lg * 4 + 3);
#pragma unroll
        for (int ni = 0; ni < 8; ++ni) {
            o[ni][0] *= fb0; o[ni][1] *= fb1; o[ni][2] *= fb2; o[ni][3] *= fb3;
        }

        // P -> bf16 A-frag (slot (g,j) -> kv = 4g + (j&3) + 16*(j>>2))
        bf16x8 pa;
        pa[0] = (__bf16)p0; pa[1] = (__bf16)p1; pa[2] = (__bf16)p2; pa[3] = (__bf16)p3;
        pa[4] = (__bf16)p4; pa[5] = (__bf16)p5; pa[6] = (__bf16)p6; pa[7] = (__bf16)p7;

        // PV: O[16q x 128d] += P @ V, 8 col-tiles
#pragma unroll
        for (int ni = 0; ni < 8; ++ni) {
            const int n = ni * 16 + lr;
            const char* vrow = (const char*)vs + n * 72;
            const bf16x4 vlo = *(const bf16x4*)(vrow + lg * 8);
            const bf16x4 vhi = *(const bf16x4*)(vrow + 32 + lg * 8);
            bf16x8 vf;
            vf[0] = vlo[0]; vf[1] = vlo[1]; vf[2] = vlo[2]; vf[3] = vlo[3];
            vf[4] = vhi[0]; vf[5] = vhi[1]; vf[6] = vhi[2]; vf[7] = vhi[3];
            o[ni] = __builtin_amdgcn_mfma_f32_16x16x32_bf16(pa, vf, o[ni], 0, 0, 0);
        }
    }

    // epilogue: divide by l (broadcast per O-row), store fp32
    const float linv = 1.f / l_run;
    const float lb0 = __shfl(linv, lg * 4 + 0);
    const float lb1 = __shfl(linv, lg * 4 + 1);
    const float lb2 = __shfl(linv, lg * 4 + 2);
    const float lb3 = __shfl(linv, lg * 4 + 3);
    float* ob = out + ((size_t)(b << 11) + qrow_base) * H_;
#pragma unroll
    for (int ni = 0; ni < 8; ++ni) {
        const int col = ni * 16 + lr;
        ob[(lg * 4 + 0) * H_ + col] = o[ni][0] * lb0;
        ob[(lg * 4 + 1) * H_ + col] = o[ni][1] * lb1;
        ob[(lg * 4 + 2) * H_ + col] = o[ni][2] * lb2;
        ob[(lg * 4 + 3) * H_ + col] = o[ni][3] * lb3;
    }
}

extern "C" void kernel_launch(void* const* d_in, const int* in_sizes, int n_in,
                              void* d_out, int out_size, void* d_ws, size_t ws_size,
                              hipStream_t stream) {
    const float* x  = (const float*)d_in[0];
    const float* Wk = (const float*)d_in[1];
    const float* Wq = (const float*)d_in[2];
    const float* Wv = (const float*)d_in[3];
    float* out = (float*)d_out;

    u16* xb  = (u16*)d_ws;                 // 8,388,608 elems (16 MB)
    u16* wbT = xb + 8388608;               // 393,216 elems (768 KB)
    u16* qb  = wbT + 393216;               // 1,048,576 elems (2 MB)
    u16* kb  = qb + 1048576;               // 2 MB
    u16* vT  = kb + 1048576;               // 2 MB  (total ~23.9 MB)

    convert_x<<<4096, 256, 0, stream>>>(x, xb);
    convert_w<<<1536, 256, 0, stream>>>(Wq, Wk, Wv, wbT);
    gemm_qkv<<<dim3(128, 3), 256, 0, stream>>>(xb, wbT, qb, kb, vT);
    attn_mfma<<<dim3(64, 4), 128, 0, stream>>>(qb, kb, vT, out);
}

// Round 3
// 65.966 us; speedup vs baseline: 6.5871x; 1.4922x over previous
//
#include <hip/hip_runtime.h>
#include <hip/hip_bf16.h>
#include <math.h>

#define B_ 4
#define T_ 2048
#define C_ 1024
#define H_ 128
#define SCALE 0.088388347648318447f   // 1/sqrt(128)

typedef unsigned short u16;
typedef __bf16 bf16x8 __attribute__((ext_vector_type(8)));
typedef __bf16 bf16x4 __attribute__((ext_vector_type(4)));
typedef float  f32x4  __attribute__((ext_vector_type(4)));
typedef u16    u16x8  __attribute__((ext_vector_type(8)));
typedef u16    u16x4  __attribute__((ext_vector_type(4)));

__device__ __forceinline__ u16 f2bf(float f) {
    __hip_bfloat16 h = __float2bfloat16(f);
    return __builtin_bit_cast(u16, h);
}

// async global->LDS, 16B per lane. lds dst must be wave-uniform base (HW adds lane*16).
__device__ __forceinline__ void load_lds16(const void* g, void* l) {
    __builtin_amdgcn_global_load_lds(
        (const __attribute__((address_space(1))) unsigned int*)g,
        (__attribute__((address_space(3))) unsigned int*)l, 16, 0, 0);
}

// ---------------------------------------------------------------------------
// convert x (fp32) -> xb (bf16), 8 elems/thread
// ---------------------------------------------------------------------------
__global__ __launch_bounds__(256) void convert_x(const float* __restrict__ x,
                                                 u16* __restrict__ xb) {
    const size_t i = ((size_t)blockIdx.x * 256 + threadIdx.x) * 8;
    const float4 a = *(const float4*)&x[i];
    const float4 b = *(const float4*)&x[i + 4];
    u16x8 r;
    r[0] = f2bf(a.x); r[1] = f2bf(a.y); r[2] = f2bf(a.z); r[3] = f2bf(a.w);
    r[4] = f2bf(b.x); r[5] = f2bf(b.y); r[6] = f2bf(b.z); r[7] = f2bf(b.w);
    *(u16x8*)&xb[i] = r;
}

// ---------------------------------------------------------------------------
// convert + transpose W: wbT[s][n][k] = W_s[k][n] (bf16), SCALE folded into Wq
// ---------------------------------------------------------------------------
__global__ __launch_bounds__(256) void convert_w(const float* __restrict__ Wq,
                                                 const float* __restrict__ Wk,
                                                 const float* __restrict__ Wv,
                                                 u16* __restrict__ wbT) {
    const int id = blockIdx.x * 256 + threadIdx.x;      // < 3*131072
    const int s = id >> 17;
    const int r = id & 131071;
    const int k = r >> 7, n = r & 127;
    const float* W = (s == 0) ? Wq : (s == 1) ? Wk : Wv;
    float v = W[k * 128 + n];
    if (s == 0) v *= SCALE;
    wbT[(s << 17) + (n << 10) + k] = f2bf(v);
}

// ---------------------------------------------------------------------------
// QKV GEMM, bf16 MFMA. grid (128, 3), block 256 (4 waves, 2x2).
// Tile 64(M) x 128(N), BK=64. q,k stored row-major bf16; v stored transposed.
// ---------------------------------------------------------------------------
__global__ __launch_bounds__(256) void gemm_qkv(
    const u16* __restrict__ xb, const u16* __restrict__ wbT,
    u16* __restrict__ qb, u16* __restrict__ kb, u16* __restrict__ vT)
{
    __shared__ u16 xs[4096];   // [64][64] bf16, 128B rows, swizzle ^((row&7)<<4)
    __shared__ u16 ws[8192];   // [128 n][64 k] bf16, 128B rows, same swizzle

    const int tid = threadIdx.x;
    const int w = tid >> 6, lane = tid & 63, lg = lane >> 4, lr = lane & 15;
    const int wm = w >> 1, wn = w & 1;
    const int s = blockIdx.y;
    const int m0 = blockIdx.x * 64;
    const u16* wsrc = wbT + (s << 17);

    f32x4 acc[2][4] = {};

    for (int k0 = 0; k0 < C_; k0 += 64) {
        __syncthreads();
        // stage x tile (8KB): 2 x 1KB chunks per wave, pre-swizzled source
#pragma unroll
        for (int i = 0; i < 2; ++i) {
            const unsigned o = (unsigned)(w * 2 + i) * 1024u + (unsigned)lane * 16u;
            const unsigned o2 = o ^ (((o >> 7) & 7u) << 4);
            const unsigned row = o2 >> 7, col = (o2 & 127u) >> 1;
            load_lds16(xb + (size_t)(m0 + row) * C_ + k0 + col, &xs[(w * 2 + i) * 512]);
        }
        // stage W^T tile (16KB): 4 chunks per wave
#pragma unroll
        for (int i = 0; i < 4; ++i) {
            const unsigned o = (unsigned)(w * 4 + i) * 1024u + (unsigned)lane * 16u;
            const unsigned o2 = o ^ (((o >> 7) & 7u) << 4);
            const unsigned row = o2 >> 7, col = (o2 & 127u) >> 1;
            load_lds16(wsrc + (size_t)row * C_ + k0 + col, &ws[(w * 4 + i) * 512]);
        }
        __syncthreads();

#pragma unroll
        for (int kc = 0; kc < 2; ++kc) {
            bf16x8 af[2], bfr[4];
#pragma unroll
            for (int mi = 0; mi < 2; ++mi) {
                const int row = wm * 32 + mi * 16 + lr;
                const unsigned byte = (unsigned)(kc * 64 + lg * 16) ^ (((unsigned)row & 7u) << 4);
                af[mi] = *(const bf16x8*)((const char*)xs + row * 128 + byte);
            }
#pragma unroll
            for (int ni = 0; ni < 4; ++ni) {
                const int n = wn * 64 + ni * 16 + lr;
                const unsigned byte = (unsigned)(kc * 64 + lg * 16) ^ (((unsigned)n & 7u) << 4);
                bfr[ni] = *(const bf16x8*)((const char*)ws + n * 128 + byte);
            }
#pragma unroll
            for (int mi = 0; mi < 2; ++mi)
#pragma unroll
                for (int ni = 0; ni < 4; ++ni)
                    acc[mi][ni] = __builtin_amdgcn_mfma_f32_16x16x32_bf16(
                        af[mi], bfr[ni], acc[mi][ni], 0, 0, 0);
        }
    }

    if (s < 2) {
        u16* dst = (s == 0) ? qb : kb;
#pragma unroll
        for (int mi = 0; mi < 2; ++mi)
#pragma unroll
            for (int ni = 0; ni < 4; ++ni) {
                const int trow = m0 + wm * 32 + mi * 16 + lg * 4;
                const int col = wn * 64 + ni * 16 + lr;
#pragma unroll
                for (int r = 0; r < 4; ++r)
                    dst[(size_t)(trow + r) * H_ + col] = f2bf(acc[mi][ni][r]);
            }
    } else {
        // v stored transposed: vT[b][d][t]
#pragma unroll
        for (int mi = 0; mi < 2; ++mi)
#pragma unroll
            for (int ni = 0; ni < 4; ++ni) {
                const int trow = m0 + wm * 32 + mi * 16 + lg * 4;
                const int bb = trow >> 11, t = trow & 2047;
                const int d = wn * 64 + ni * 16 + lr;
                u16x4 pk;
                pk[0] = f2bf(acc[mi][ni][0]); pk[1] = f2bf(acc[mi][ni][1]);
                pk[2] = f2bf(acc[mi][ni][2]); pk[3] = f2bf(acc[mi][ni][3]);
                *(u16x4*)&vT[((size_t)bb * 128 + d) * 2048 + t] = pk;
            }
    }
}

// ---------------------------------------------------------------------------
// Flash attention, split-K over KV chunks of 16 tiles (512 kv positions).
// grid (64 jt, 4 split, 4 batch), block 128 (2 waves, 16 q-rows each).
// Writes unnormalized partials: po[slot][32][128] f32, ml[slot][2][32].
// slot = (g+1)*(8g+r)+s per batch, g=jt>>4, r=jt&15 (compact, 160/batch).
// ---------------------------------------------------------------------------
__global__ __launch_bounds__(128) void attn_split(
    const u16* __restrict__ qb, const u16* __restrict__ kb,
    const u16* __restrict__ vT, float* __restrict__ po, float* __restrict__ ml)
{
    __shared__ u16 ks[4096];        // [32][128] bf16, 256B rows, swizzle ^((row&7)<<4)
    __shared__ u16 vs[128 * 36];    // [128 d][32 kv] bf16, padded rows 72B

    const int jt = blockIdx.x, sp = blockIdx.y, b = blockIdx.z;
    if (sp * 16 > jt) return;                   // inactive split
    const int kt0 = sp * 16;
    const int kt_end = min(kt0 + 16, jt + 1);

    const int tid = threadIdx.x;
    const int w = tid >> 6, lane = tid & 63, lg = lane >> 4, lr = lane & 15;
    const int qrow_base = jt * 32 + w * 16;

    // Q fragments: d-slot map = kc*32 + lg*8 + j  (matches K-frag map)
    const u16* qp = qb + ((size_t)(b << 11) + qrow_base + lr) * H_;
    bf16x8 qf[4];
#pragma unroll
    for (int kc = 0; kc < 4; ++kc)
        qf[kc] = *(const bf16x8*)&qp[kc * 32 + lg * 8];

    f32x4 o[8] = {};
    float m_run = -INFINITY, l_run = 0.f;

    for (int kt = kt0; kt < kt_end; ++kt) {
        __syncthreads();   // protect prev tile's reads
        // stage K tile (8KB) via global_load_lds, pre-swizzled source
        const u16* kbase = kb + ((size_t)(b << 11) + kt * 32) * H_;
#pragma unroll
        for (int i = 0; i < 4; ++i) {
            const unsigned o_ = (unsigned)(w * 4 + i) * 1024u + (unsigned)lane * 16u;
            const unsigned o2 = o_ ^ (((o_ >> 8) & 7u) << 4);
            const unsigned row = o2 >> 8, colb = o2 & 255u;
            load_lds16((const char*)kbase + row * 256 + colb, &ks[(w * 4 + i) * 512]);
        }
        // stage V^T tile (reg-staged, padded rows)
        const u16* vbase = vT + (size_t)b * 128 * 2048 + (size_t)kt * 32;
#pragma unroll
        for (int i = 0; i < 4; ++i) {
            const int idx = i * 128 + tid;         // 0..511
            const int d = idx >> 2, c = idx & 3;
            const u16x8 tmp = *(const u16x8*)&vbase[(size_t)d * 2048 + c * 8];
            *(u16x8*)((char*)vs + d * 72 + c * 16) = tmp;
        }
        __syncthreads();

        // S^T = K @ Q^T : two 16-kv subtiles, accumulate over d (4 chunks of 32)
        f32x4 s0 = {0.f, 0.f, 0.f, 0.f}, s1 = {0.f, 0.f, 0.f, 0.f};
        const unsigned swz = ((unsigned)lr & 7u) << 4;
#pragma unroll
        for (int kc = 0; kc < 4; ++kc) {
            const unsigned byte = ((unsigned)(kc * 64 + lg * 16)) ^ swz;
            const bf16x8 kf0 = *(const bf16x8*)((const char*)ks + lr * 256 + byte);
            const bf16x8 kf1 = *(const bf16x8*)((const char*)ks + lr * 256 + 4096 + byte);
            s0 = __builtin_amdgcn_mfma_f32_16x16x32_bf16(kf0, qf[kc], s0, 0, 0, 0);
            s1 = __builtin_amdgcn_mfma_f32_16x16x32_bf16(kf1, qf[kc], s1, 0, 0, 0);
        }

        // causal mask (diagonal tile only). kv-offset = sub*16 + lg*4 + r, q-offset = w*16 + lr
        if (kt == jt) {
            const int qq = w * 16 + lr;
#pragma unroll
            for (int r = 0; r < 4; ++r) {
                if (lg * 4 + r > qq)      s0[r] = -INFINITY;
                if (16 + lg * 4 + r > qq) s1[r] = -INFINITY;
            }
        }

        // online softmax (q-row = lr, replicated across 4 lane-groups)
        float mt = fmaxf(fmaxf(fmaxf(s0[0], s0[1]), fmaxf(s0[2], s0[3])),
                         fmaxf(fmaxf(s1[0], s1[1]), fmaxf(s1[2], s1[3])));
        mt = fmaxf(mt, __shfl_xor(mt, 16));
        mt = fmaxf(mt, __shfl_xor(mt, 32));
        const float mn = fmaxf(m_run, mt);
        const float p0 = __expf(s0[0] - mn), p1 = __expf(s0[1] - mn);
        const float p2 = __expf(s0[2] - mn), p3 = __expf(s0[3] - mn);
        const float p4 = __expf(s1[0] - mn), p5 = __expf(s1[1] - mn);
        const float p6 = __expf(s1[2] - mn), p7 = __expf(s1[3] - mn);
        float sum = ((p0 + p1) + (p2 + p3)) + ((p4 + p5) + (p6 + p7));
        sum += __shfl_xor(sum, 16);
        sum += __shfl_xor(sum, 32);
        const float f = __expf(m_run - mn);   // first tile: exp(-inf)=0
        l_run = l_run * f + sum;
        m_run = mn;

        // rescale O: broadcast f per O-row ((lg*4+r) is the q-offset of acc reg r)
        const float fb0 = __shfl(f, lg * 4 + 0);
        const float fb1 = __shfl(f, lg * 4 + 1);
        const float fb2 = __shfl(f, lg * 4 + 2);
        const float fb3 = __shfl(f, lg * 4 + 3);
#pragma unroll
        for (int ni = 0; ni < 8; ++ni) {
            o[ni][0] *= fb0; o[ni][1] *= fb1; o[ni][2] *= fb2; o[ni][3] *= fb3;
        }

        // P -> bf16 A-frag (slot (g,j) -> kv = 4g + (j&3) + 16*(j>>2))
        bf16x8 pa;
        pa[0] = (__bf16)p0; pa[1] = (__bf16)p1; pa[2] = (__bf16)p2; pa[3] = (__bf16)p3;
        pa[4] = (__bf16)p4; pa[5] = (__bf16)p5; pa[6] = (__bf16)p6; pa[7] = (__bf16)p7;

        // PV: O[16q x 128d] += P @ V, 8 col-tiles
#pragma unroll
        for (int ni = 0; ni < 8; ++ni) {
            const int n = ni * 16 + lr;
            const char* vrow = (const char*)vs + n * 72;
            const bf16x4 vlo = *(const bf16x4*)(vrow + lg * 8);
            const bf16x4 vhi = *(const bf16x4*)(vrow + 32 + lg * 8);
            bf16x8 vf;
            vf[0] = vlo[0]; vf[1] = vlo[1]; vf[2] = vlo[2]; vf[3] = vlo[3];
            vf[4] = vhi[0]; vf[5] = vhi[1]; vf[6] = vhi[2]; vf[7] = vhi[3];
            o[ni] = __builtin_amdgcn_mfma_f32_16x16x32_bf16(pa, vf, o[ni], 0, 0, 0);
        }
    }

    // write partials (unnormalized O, plus m and l)
    const int g = jt >> 4, rr = jt & 15;
    const int slot = (g + 1) * (8 * g + rr) + sp;
    float* pob = po + (size_t)(b * 160 + slot) * 32 * 128;
#pragma unroll
    for (int ni = 0; ni < 8; ++ni) {
        const int col = ni * 16 + lr;
#pragma unroll
        for (int rj = 0; rj < 4; ++rj)
            pob[(w * 16 + lg * 4 + rj) * 128 + col] = o[ni][rj];
    }
    if (lg == 0) {
        float* mlb = ml + (size_t)(b * 160 + slot) * 64;
        mlb[w * 16 + lr] = m_run;
        mlb[32 + w * 16 + lr] = l_run;
    }
}

// ---------------------------------------------------------------------------
// Combine split-K partials. grid (256, 4), block 256: 8 rows/block, 32 thr/row
// (each thread 4 d-columns via float4).
// ---------------------------------------------------------------------------
__global__ __launch_bounds__(256) void attn_combine(
    const float* __restrict__ po, const float* __restrict__ ml,
    float* __restrict__ out)
{
    const int rid = (blockIdx.x << 3) + (threadIdx.x >> 5);   // row in batch, 0..2047
    const int b = blockIdx.y;
    const int d4 = (threadIdx.x & 31) * 4;
    const int jt = rid >> 5, row = rid & 31;
    const int g = jt >> 4, rr = jt & 15;
    const int slot0 = (g + 1) * (8 * g + rr);
    const int c = g + 1;                                       // active splits

    float M = -INFINITY;
#pragma unroll
    for (int si = 0; si < 4; ++si)
        if (si < c) M = fmaxf(M, ml[(size_t)(b * 160 + slot0 + si) * 64 + row]);

    float L = 0.f;
    float a0 = 0.f, a1 = 0.f, a2 = 0.f, a3 = 0.f;
#pragma unroll
    for (int si = 0; si < 4; ++si) {
        if (si < c) {
            const float* mlb = ml + (size_t)(b * 160 + slot0 + si) * 64;
            const float wgt = __expf(mlb[row] - M);
            L += wgt * mlb[32 + row];
            const float4 t = *(const float4*)&po[((size_t)(b * 160 + slot0 + si) * 32 + row) * 128 + d4];
            a0 = fmaf(wgt, t.x, a0); a1 = fmaf(wgt, t.y, a1);
            a2 = fmaf(wgt, t.z, a2); a3 = fmaf(wgt, t.w, a3);
        }
    }
    const float inv = 1.f / L;
    *(float4*)&out[((size_t)(b << 11) + rid) * H_ + d4] =
        make_float4(a0 * inv, a1 * inv, a2 * inv, a3 * inv);
}

extern "C" void kernel_launch(void* const* d_in, const int* in_sizes, int n_in,
                              void* d_out, int out_size, void* d_ws, size_t ws_size,
                              hipStream_t stream) {
    const float* x  = (const float*)d_in[0];
    const float* Wk = (const float*)d_in[1];
    const float* Wq = (const float*)d_in[2];
    const float* Wv = (const float*)d_in[3];
    float* out = (float*)d_out;

    u16* xb  = (u16*)d_ws;                 // 16 MB  (dead after gemm_qkv -> reused as po)
    u16* wbT = xb + 8388608;               // 768 KB (dead after gemm_qkv -> reused as ml)
    u16* qb  = wbT + 393216;               // 2 MB
    u16* kb  = qb + 1048576;               // 2 MB
    u16* vT  = kb + 1048576;               // 2 MB  (total ~23.9 MB)

    float* po = (float*)d_ws;                               // 10.5 MB, aliases xb
    float* ml = (float*)((char*)d_ws + 16777216);           // 160 KB, aliases wbT

    convert_x<<<4096, 256, 0, stream>>>(x, xb);
    convert_w<<<1536, 256, 0, stream>>>(Wq, Wk, Wv, wbT);
    gemm_qkv<<<dim3(128, 3), 256, 0, stream>>>(xb, wbT, qb, kb, vT);
    attn_split<<<dim3(64, 4, 4), 128, 0, stream>>>(qb, kb, vT, po, ml);
    attn_combine<<<dim3(256, 4), 256, 0, stream>>>(po, ml, out);
}

// Round 5
// 64.611 us; speedup vs baseline: 6.7253x; 1.0210x over previous
//
#include <hip/hip_runtime.h>
#include <hip/hip_bf16.h>
#include <math.h>

#define B_ 4
#define T_ 2048
#define C_ 1024
#define H_ 128
#define SCALE 0.088388347648318447f   // 1/sqrt(128)

typedef unsigned short u16;
typedef __bf16 bf16x8 __attribute__((ext_vector_type(8)));
typedef __bf16 bf16x4 __attribute__((ext_vector_type(4)));
typedef float  f32x4  __attribute__((ext_vector_type(4)));
typedef u16    u16x8  __attribute__((ext_vector_type(8)));
typedef u16    u16x4  __attribute__((ext_vector_type(4)));

// ws byte offsets (ws is ~256MB; everything disjoint, no aliasing)
#define PO_OFF  0u            // f32 [4][288][32][128]  = 18,874,368 B
#define ML_OFF  18874368u     // f32 [4][288][64]       =    294,912 B
#define WBT_OFF 19169280u     // bf16 [3][128][1024]    =    786,432 B
#define QB_OFF  19955712u     // bf16 [4][2048][128]    =  2,097,152 B
#define KB_OFF  22052864u     // bf16 [4][2048][128]    =  2,097,152 B
#define VT_OFF  24150016u     // bf16 [4][128][2048]    =  2,097,152 B

__device__ __forceinline__ u16 f2bf(float f) {
    __hip_bfloat16 h = __float2bfloat16(f);
    return __builtin_bit_cast(u16, h);
}

// async global->LDS, 16B per lane. lds dst must be wave-uniform base (HW adds lane*16).
__device__ __forceinline__ void load_lds16(const void* g, void* l) {
    __builtin_amdgcn_global_load_lds(
        (const __attribute__((address_space(1))) unsigned int*)g,
        (__attribute__((address_space(3))) unsigned int*)l, 16, 0, 0);
}

// ---------------------------------------------------------------------------
// convert + transpose W: wbT[s][n][k] = W_s[k][n] (bf16), SCALE folded into Wq
// ---------------------------------------------------------------------------
__global__ __launch_bounds__(256) void convert_w(const float* __restrict__ Wq,
                                                 const float* __restrict__ Wk,
                                                 const float* __restrict__ Wv,
                                                 u16* __restrict__ wbT) {
    const int id = blockIdx.x * 256 + threadIdx.x;      // < 3*131072
    const int s = id >> 17;
    const int r = id & 131071;
    const int k = r >> 7, n = r & 127;
    const float* W = (s == 0) ? Wq : (s == 1) ? Wk : Wv;
    float v = W[k * 128 + n];
    if (s == 0) v *= SCALE;
    wbT[(s << 17) + (n << 10) + k] = f2bf(v);
}

// ---------------------------------------------------------------------------
// QKV GEMM, bf16 MFMA, x read as fp32 and converted in-kernel (reg-staged).
// grid (128, 3), block 256 (4 waves, 2x2). Tile 64(M)x128(N), BK=64.
// q,k stored row-major bf16; v stored transposed vT[b][d][t].
// ---------------------------------------------------------------------------
__global__ __launch_bounds__(256) void gemm_qkv(
    const float* __restrict__ x, const u16* __restrict__ wbT,
    u16* __restrict__ qb, u16* __restrict__ kb, u16* __restrict__ vT)
{
    __shared__ u16 xs[4096];   // [64][64] bf16, 128B rows, swizzle ^((row&7)<<4)
    __shared__ u16 ws[8192];   // [128 n][64 k] bf16, 128B rows, same swizzle

    const int tid = threadIdx.x;
    const int w = tid >> 6, lane = tid & 63, lg = lane >> 4, lr = lane & 15;
    const int wm = w >> 1, wn = w & 1;
    const int s = blockIdx.y;
    const int m0 = blockIdx.x * 64;
    const u16* wsrc = wbT + (s << 17);

    // x staging role: 4 threads per row, 32B bf16 (=16 fp32) per thread
    const int xrow = tid >> 2;       // 0..63
    const int xseg = tid & 3;        // 0..3

    f32x4 acc[2][4] = {};

    for (int k0 = 0; k0 < C_; k0 += 64) {
        // issue x fp32 loads early (global reads, no LDS hazard)
        const float4* xp = (const float4*)&x[(size_t)(m0 + xrow) * C_ + k0 + xseg * 16];
        const float4 f0 = xp[0], f1 = xp[1], f2 = xp[2], f3 = xp[3];

        __syncthreads();   // prev iteration's reads done before overwrite
        // stage W^T tile (16KB) via global_load_lds, pre-swizzled source
#pragma unroll
        for (int i = 0; i < 4; ++i) {
            const unsigned o = (unsigned)(w * 4 + i) * 1024u + (unsigned)lane * 16u;
            const unsigned o2 = o ^ (((o >> 7) & 7u) << 4);
            const unsigned row = o2 >> 7, col = (o2 & 127u) >> 1;
            load_lds16(wsrc + (size_t)row * C_ + k0 + col, &ws[(w * 4 + i) * 512]);
        }
        // convert + ds_write x tile (swizzled)
        {
            u16x8 lo, hi;
            lo[0] = f2bf(f0.x); lo[1] = f2bf(f0.y); lo[2] = f2bf(f0.z); lo[3] = f2bf(f0.w);
            lo[4] = f2bf(f1.x); lo[5] = f2bf(f1.y); lo[6] = f2bf(f1.z); lo[7] = f2bf(f1.w);
            hi[0] = f2bf(f2.x); hi[1] = f2bf(f2.y); hi[2] = f2bf(f2.z); hi[3] = f2bf(f2.w);
            hi[4] = f2bf(f3.x); hi[5] = f2bf(f3.y); hi[6] = f2bf(f3.z); hi[7] = f2bf(f3.w);
            const unsigned sw = ((unsigned)xrow & 7u) << 4;
            char* rb = (char*)xs + xrow * 128;
            *(u16x8*)(rb + (((unsigned)xseg * 32 + 0) ^ sw)) = lo;
            *(u16x8*)(rb + (((unsigned)xseg * 32 + 16) ^ sw)) = hi;
        }
        __syncthreads();

#pragma unroll
        for (int kc = 0; kc < 2; ++kc) {
            bf16x8 af[2], bfr[4];
#pragma unroll
            for (int mi = 0; mi < 2; ++mi) {
                const int row = wm * 32 + mi * 16 + lr;
                const unsigned byte = (unsigned)(kc * 64 + lg * 16) ^ (((unsigned)row & 7u) << 4);
                af[mi] = *(const bf16x8*)((const char*)xs + row * 128 + byte);
            }
#pragma unroll
            for (int ni = 0; ni < 4; ++ni) {
                const int n = wn * 64 + ni * 16 + lr;
                const unsigned byte = (unsigned)(kc * 64 + lg * 16) ^ (((unsigned)n & 7u) << 4);
                bfr[ni] = *(const bf16x8*)((const char*)ws + n * 128 + byte);
            }
#pragma unroll
            for (int mi = 0; mi < 2; ++mi)
#pragma unroll
                for (int ni = 0; ni < 4; ++ni)
                    acc[mi][ni] = __builtin_amdgcn_mfma_f32_16x16x32_bf16(
                        af[mi], bfr[ni], acc[mi][ni], 0, 0, 0);
        }
    }

    if (s < 2) {
        u16* dst = (s == 0) ? qb : kb;
#pragma unroll
        for (int mi = 0; mi < 2; ++mi)
#pragma unroll
            for (int ni = 0; ni < 4; ++ni) {
                const int trow = m0 + wm * 32 + mi * 16 + lg * 4;
                const int col = wn * 64 + ni * 16 + lr;
#pragma unroll
                for (int r = 0; r < 4; ++r)
                    dst[(size_t)(trow + r) * H_ + col] = f2bf(acc[mi][ni][r]);
            }
    } else {
        // v stored transposed: vT[b][d][t]
#pragma unroll
        for (int mi = 0; mi < 2; ++mi)
#pragma unroll
            for (int ni = 0; ni < 4; ++ni) {
                const int trow = m0 + wm * 32 + mi * 16 + lg * 4;
                const int bb = trow >> 11, t = trow & 2047;
                const int d = wn * 64 + ni * 16 + lr;
                u16x4 pk;
                pk[0] = f2bf(acc[mi][ni][0]); pk[1] = f2bf(acc[mi][ni][1]);
                pk[2] = f2bf(acc[mi][ni][2]); pk[3] = f2bf(acc[mi][ni][3]);
                *(u16x4*)&vT[((size_t)bb * 128 + d) * 2048 + t] = pk;
            }
    }
}

// ---------------------------------------------------------------------------
// Flash attention, split-K over KV chunks of 8 tiles (256 kv positions),
// double-buffered K/V staging (prefetch t+1 while computing t).
// grid (64 jt, 8 split, 4 batch), block 128 (2 waves, 16 q-rows each).
// Partials: po[slot][32][128] f32, ml[slot][2][32] f32.
// slot = (g+1)*(4g+r)+sp, g=jt>>3, r=jt&7 (compact, 288/batch).
// ---------------------------------------------------------------------------
__global__ __launch_bounds__(128) void attn_split(
    const u16* __restrict__ qb, const u16* __restrict__ kb,
    const u16* __restrict__ vT, float* __restrict__ po, float* __restrict__ ml)
{
    __shared__ u16 ks[2][4096];      // [32][128] bf16, 256B rows (8KB/buf), swizzle ^((row&7)<<4)
    __shared__ u16 vs[2][128 * 36];  // [128 d][32 kv] bf16, padded rows 72B

    const int jt = blockIdx.x, sp = blockIdx.y, b = blockIdx.z;
    if (sp * 8 > jt) return;                    // inactive split
    const int kt0 = sp * 8;
    const int kt_end = min(kt0 + 8, jt + 1);

    const int tid = threadIdx.x;
    const int w = tid >> 6, lane = tid & 63, lg = lane >> 4, lr = lane & 15;
    const int qrow_base = jt * 32 + w * 16;

    const u16* kbB = kb + ((size_t)(b << 11)) * H_;
    const u16* vbB = vT + (size_t)b * 128 * 2048;

    // K staging addressing (per wave: 4 x 1KB chunks, pre-swizzled source)
    unsigned krow[4], kcolb[4];
#pragma unroll
    for (int i = 0; i < 4; ++i) {
        const unsigned o_ = (unsigned)(w * 4 + i) * 1024u + (unsigned)lane * 16u;
        const unsigned o2 = o_ ^ (((o_ >> 8) & 7u) << 4);
        krow[i] = o2 >> 8; kcolb[i] = o2 & 255u;
    }
    // V staging addressing (4 x u16x8 per thread)
    int vd[4], vc[4];
#pragma unroll
    for (int i = 0; i < 4; ++i) {
        const int idx = i * 128 + tid;
        vd[i] = idx >> 2; vc[i] = idx & 3;
    }

    // Q fragments: d-slot map = kc*32 + lg*8 + j  (matches K-frag map)
    const u16* qp = qb + ((size_t)(b << 11) + qrow_base + lr) * H_;
    bf16x8 qf[4];
#pragma unroll
    for (int kc = 0; kc < 4; ++kc)
        qf[kc] = *(const bf16x8*)&qp[kc * 32 + lg * 8];

    // ---- prologue: stage tile kt0 into buffer 0
    u16x8 vr[4];
    {
        const u16* kbase = kbB + (size_t)kt0 * 32 * H_;
#pragma unroll
        for (int i = 0; i < 4; ++i)
            load_lds16((const char*)kbase + krow[i] * 256 + kcolb[i], &ks[0][(w * 4 + i) * 512]);
        const u16* vbase = vbB + (size_t)kt0 * 32;
#pragma unroll
        for (int i = 0; i < 4; ++i)
            vr[i] = *(const u16x8*)&vbase[(size_t)vd[i] * 2048 + vc[i] * 8];
#pragma unroll
        for (int i = 0; i < 4; ++i)
            *(u16x8*)((char*)vs[0] + vd[i] * 72 + vc[i] * 16) = vr[i];
    }
    __syncthreads();

    f32x4 o[8] = {};
    float m_run = -INFINITY, l_run = 0.f;
    int cur = 0;

    for (int kt = kt0; kt < kt_end; ++kt) {
        const bool pf = (kt + 1 < kt_end);
        // ---- issue prefetch of tile kt+1 into buffer cur^1
        if (pf) {
            const u16* kbase = kbB + (size_t)(kt + 1) * 32 * H_;
#pragma unroll
            for (int i = 0; i < 4; ++i)
                load_lds16((const char*)kbase + krow[i] * 256 + kcolb[i],
                           &ks[cur ^ 1][(w * 4 + i) * 512]);
            const u16* vbase = vbB + (size_t)(kt + 1) * 32;
#pragma unroll
            for (int i = 0; i < 4; ++i)
                vr[i] = *(const u16x8*)&vbase[(size_t)vd[i] * 2048 + vc[i] * 8];
        }

        // ---- compute tile kt from buffer cur
        // S^T = K @ Q^T : two 16-kv subtiles, accumulate over d (4 chunks of 32)
        f32x4 s0 = {0.f, 0.f, 0.f, 0.f}, s1 = {0.f, 0.f, 0.f, 0.f};
        const unsigned swz = ((unsigned)lr & 7u) << 4;
#pragma unroll
        for (int kc = 0; kc < 4; ++kc) {
            const unsigned byte = ((unsigned)(kc * 64 + lg * 16)) ^ swz;
            const bf16x8 kf0 = *(const bf16x8*)((const char*)ks[cur] + lr * 256 + byte);
            const bf16x8 kf1 = *(const bf16x8*)((const char*)ks[cur] + lr * 256 + 4096 + byte);
            s0 = __builtin_amdgcn_mfma_f32_16x16x32_bf16(kf0, qf[kc], s0, 0, 0, 0);
            s1 = __builtin_amdgcn_mfma_f32_16x16x32_bf16(kf1, qf[kc], s1, 0, 0, 0);
        }

        // causal mask (diagonal tile only). kv-offset = sub*16 + lg*4 + r, q-offset = w*16 + lr
        if (kt == jt) {
            const int qq = w * 16 + lr;
#pragma unroll
            for (int r = 0; r < 4; ++r) {
                if (lg * 4 + r > qq)      s0[r] = -INFINITY;
                if (16 + lg * 4 + r > qq) s1[r] = -INFINITY;
            }
        }

        // online softmax (q-row = lr, replicated across 4 lane-groups)
        float mt = fmaxf(fmaxf(fmaxf(s0[0], s0[1]), fmaxf(s0[2], s0[3])),
                         fmaxf(fmaxf(s1[0], s1[1]), fmaxf(s1[2], s1[3])));
        mt = fmaxf(mt, __shfl_xor(mt, 16));
        mt = fmaxf(mt, __shfl_xor(mt, 32));
        const float mn = fmaxf(m_run, mt);
        const float p0 = __expf(s0[0] - mn), p1 = __expf(s0[1] - mn);
        const float p2 = __expf(s0[2] - mn), p3 = __expf(s0[3] - mn);
        const float p4 = __expf(s1[0] - mn), p5 = __expf(s1[1] - mn);
        const float p6 = __expf(s1[2] - mn), p7 = __expf(s1[3] - mn);
        float sum = ((p0 + p1) + (p2 + p3)) + ((p4 + p5) + (p6 + p7));
        sum += __shfl_xor(sum, 16);
        sum += __shfl_xor(sum, 32);
        const float f = __expf(m_run - mn);   // first tile: exp(-inf)=0
        l_run = l_run * f + sum;
        m_run = mn;

        // rescale O: broadcast f per O-row ((lg*4+r) is the q-offset of acc reg r)
        const float fb0 = __shfl(f, lg * 4 + 0);
        const float fb1 = __shfl(f, lg * 4 + 1);
        const float fb2 = __shfl(f, lg * 4 + 2);
        const float fb3 = __shfl(f, lg * 4 + 3);
#pragma unroll
        for (int ni = 0; ni < 8; ++ni) {
            o[ni][0] *= fb0; o[ni][1] *= fb1; o[ni][2] *= fb2; o[ni][3] *= fb3;
        }

        // P -> bf16 A-frag (slot (g,j) -> kv = 4g + (j&3) + 16*(j>>2))
        bf16x8 pa;
        pa[0] = (__bf16)p0; pa[1] = (__bf16)p1; pa[2] = (__bf16)p2; pa[3] = (__bf16)p3;
        pa[4] = (__bf16)p4; pa[5] = (__bf16)p5; pa[6] = (__bf16)p6; pa[7] = (__bf16)p7;

        // PV: O[16q x 128d] += P @ V, 8 col-tiles
#pragma unroll
        for (int ni = 0; ni < 8; ++ni) {
            const int n = ni * 16 + lr;
            const char* vrow = (const char*)vs[cur] + n * 72;
            const bf16x4 vlo = *(const bf16x4*)(vrow + lg * 8);
            const bf16x4 vhi = *(const bf16x4*)(vrow + 32 + lg * 8);
            bf16x8 vf;
            vf[0] = vlo[0]; vf[1] = vlo[1]; vf[2] = vlo[2]; vf[3] = vlo[3];
            vf[4] = vhi[0]; vf[5] = vhi[1]; vf[6] = vhi[2]; vf[7] = vhi[3];
            o[ni] = __builtin_amdgcn_mfma_f32_16x16x32_bf16(pa, vf, o[ni], 0, 0, 0);
        }

        // ---- land prefetched V into LDS, then barrier (drains K gloads too)
        if (pf) {
#pragma unroll
            for (int i = 0; i < 4; ++i)
                *(u16x8*)((char*)vs[cur ^ 1] + vd[i] * 72 + vc[i] * 16) = vr[i];
        }
        __syncthreads();
        cur ^= 1;
    }

    // write partials (unnormalized O, plus m and l)
    const int g = jt >> 3, rr = jt & 7;
    const int slot = (g + 1) * (4 * g + rr) + sp;
    float* pob = po + (size_t)(b * 288 + slot) * 32 * 128;
#pragma unroll
    for (int ni = 0; ni < 8; ++ni) {
        const int col = ni * 16 + lr;
#pragma unroll
        for (int rj = 0; rj < 4; ++rj)
            pob[(w * 16 + lg * 4 + rj) * 128 + col] = o[ni][rj];
    }
    if (lg == 0) {
        float* mlb = ml + (size_t)(b * 288 + slot) * 64;
        mlb[w * 16 + lr] = m_run;
        mlb[32 + w * 16 + lr] = l_run;
    }
}

// ---------------------------------------------------------------------------
// Combine split-K partials (up to 8). grid (256, 4), block 256: 8 rows/block,
// 32 thr/row, each thread 4 d-columns via float4.
// ---------------------------------------------------------------------------
__global__ __launch_bounds__(256) void attn_combine(
    const float* __restrict__ po, const float* __restrict__ ml,
    float* __restrict__ out)
{
    const int rid = (blockIdx.x << 3) + (threadIdx.x >> 5);   // row in batch, 0..2047
    const int b = blockIdx.y;
    const int d4 = (threadIdx.x & 31) * 4;
    const int jt = rid >> 5, row = rid & 31;
    const int g = jt >> 3, rr = jt & 7;
    const int slot0 = (g + 1) * (4 * g + rr);
    const int c = g + 1;                                       // active splits (1..8)

    float M = -INFINITY;
#pragma unroll
    for (int si = 0; si < 8; ++si)
        if (si < c) M = fmaxf(M, ml[(size_t)(b * 288 + slot0 + si) * 64 + row]);

    float L = 0.f;
    float a0 = 0.f, a1 = 0.f, a2 = 0.f, a3 = 0.f;
#pragma unroll
    for (int si = 0; si < 8; ++si) {
        if (si < c) {
            const float* mlb = ml + (size_t)(b * 288 + slot0 + si) * 64;
            const float wgt = __expf(mlb[row] - M);
            L += wgt * mlb[32 + row];
            const float4 t = *(const float4*)&po[((size_t)(b * 288 + slot0 + si) * 32 + row) * 128 + d4];
            a0 = fmaf(wgt, t.x, a0); a1 = fmaf(wgt, t.y, a1);
            a2 = fmaf(wgt, t.z, a2); a3 = fmaf(wgt, t.w, a3);
        }
    }
    const float inv = 1.f / L;
    *(float4*)&out[((size_t)(b << 11) + rid) * H_ + d4] =
        make_float4(a0 * inv, a1 * inv, a2 * inv, a3 * inv);
}

extern "C" void kernel_launch(void* const* d_in, const int* in_sizes, int n_in,
                              void* d_out, int out_size, void* d_ws, size_t ws_size,
                              hipStream_t stream) {
    const float* x  = (const float*)d_in[0];
    const float* Wk = (const float*)d_in[1];
    const float* Wq = (const float*)d_in[2];
    const float* Wv = (const float*)d_in[3];
    float* out = (float*)d_out;

    float* po = (float*)((char*)d_ws + PO_OFF);
    float* ml = (float*)((char*)d_ws + ML_OFF);
    u16* wbT  = (u16*)((char*)d_ws + WBT_OFF);
    u16* qb   = (u16*)((char*)d_ws + QB_OFF);
    u16* kb   = (u16*)((char*)d_ws + KB_OFF);
    u16* vT   = (u16*)((char*)d_ws + VT_OFF);

    convert_w<<<1536, 256, 0, stream>>>(Wq, Wk, Wv, wbT);
    gemm_qkv<<<dim3(128, 3), 256, 0, stream>>>(x, wbT, qb, kb, vT);
    attn_split<<<dim3(64, 8, 4), 128, 0, stream>>>(qb, kb, vT, po, ml);
    attn_combine<<<dim3(256, 4), 256, 0, stream>>>(po, ml, out);
}